// Round 2
// baseline (6927.095 us; speedup 1.0000x reference)
//
#include <hip/hip_runtime.h>

// multiplicativeNoise: dY = G(Y) o dB  (mu_strato == 0 exactly), 100-step RK4,
// per-sample gather at step idx[b] = clip(trunc(100*t[b]), 0, 99).
//
// Round-2 structure:
//  - counting-sort batch by idx; 16 elems per block, early exit at chunk max.
//  - A-build GEMM flipped: D[n][e] = sum_k G[n][k] dw_e[k]  (G-frag as MFMA A-op,
//    dw-frag as B-op). Lane gets 4 consecutive n for one elem -> packed b64 stores.
//  - TWO steps per G pass: each G tile feeds 4 MFMAs (step s and s+1 dw frags);
//    step s+1 output held bf16-packed in 32 VGPRs, written to Abuf after RK4(s).
//    Halves the per-step L2 G traffic (512KB -> 256KB per block-step).
//  - RK4: wave e reads its elem's A into 32 VGPRs (8x b128), stages need only
//    16 broadcast vbuf reads + 64 FMA each. Wave-implicit stage sync.
//  - dW prefetched one pass ahead (registers), hiding HBM latency.

typedef __attribute__((ext_vector_type(8))) short short8;
typedef __attribute__((ext_vector_type(4))) float f32x4;

#define NSTEP 100
#define BATCH 16384
#define NCHUNK 1024            // BATCH / 16
#define ISTR 72                // ushort stride per A row i (64 + 8 pad = 144B, 16B aligned)
#define ESTR 4616              // ushort stride per elem (64*72 + 8 pad = 9232B, 16B aligned)

__device__ __forceinline__ unsigned short f2bf(float f) {
  unsigned u = __float_as_uint(f);
  unsigned r = (u + 0x7FFFu + ((u >> 16) & 1u)) >> 16;   // RNE
  return (unsigned short)r;
}
__device__ __forceinline__ unsigned pack2(float a, float b) {
  return (unsigned)f2bf(a) | ((unsigned)f2bf(b) << 16);
}
__device__ __forceinline__ float bflo(unsigned u) { return __uint_as_float(u << 16); }
__device__ __forceinline__ float bfhi(unsigned u) { return __uint_as_float(u & 0xffff0000u); }

// ---------------- prep kernels ----------------

__global__ void k_cast(const float* __restrict__ G, unsigned short* __restrict__ g2, int n) {
  int i = blockIdx.x * blockDim.x + threadIdx.x;
  if (i < n) g2[i] = f2bf(G[i]);
}

__global__ void k_idx(const float* __restrict__ t, int* __restrict__ idxb, int* __restrict__ hist) {
  int b = blockIdx.x * blockDim.x + threadIdx.x;
  if (b < BATCH) {
    int ix = (int)truncf(100.0f * t[b]);       // matches jnp.trunc(n*t/T) in fp32
    ix = min(max(ix, 0), NSTEP - 1);
    idxb[b] = ix;
    atomicAdd(&hist[ix], 1);
  }
}

__global__ void k_scan(const int* __restrict__ hist, int* __restrict__ offs) {
  if (threadIdx.x == 0 && blockIdx.x == 0) {
    int run = 0;
    for (int i = 0; i < NSTEP; ++i) { offs[i] = run; run += hist[i]; }
  }
}

__global__ void k_scatter(const int* __restrict__ idxb, const int* __restrict__ offs,
                          int* __restrict__ cur, int* __restrict__ perm) {
  int b = blockIdx.x * blockDim.x + threadIdx.x;
  if (b < BATCH) {
    int ix = idxb[b];
    int pos = offs[ix] + atomicAdd(&cur[ix], 1);
    perm[pos] = b;
  }
}

// ---------------- main kernel ----------------

__device__ __forceinline__ float rk4_dot(const unsigned* Ap, const float* vr) {
  // 4 partial accumulators: FMA dep chain 16 deep instead of 64
  float a0 = 0.f, a1 = 0.f, a2 = 0.f, a3 = 0.f;
#pragma unroll
  for (int m = 0; m < 16; ++m) {
    float4 v = ((const float4*)vr)[m];      // broadcast LDS read (conflict-free)
    unsigned ua = Ap[2 * m], ub = Ap[2 * m + 1];
    a0 = fmaf(bflo(ua), v.x, a0);
    a1 = fmaf(bfhi(ua), v.y, a1);
    a2 = fmaf(bflo(ub), v.z, a2);
    a3 = fmaf(bfhi(ub), v.w, a3);
  }
  return (a0 + a1) + (a2 + a3);
}

__device__ __forceinline__ float rk4_one(const unsigned short* Ar, float* vr, float y, int lane) {
  unsigned Areg[32];                         // this elem's A row (64 bf16), registers
#pragma unroll
  for (int m = 0; m < 8; ++m) {
    uint4 q = *(const uint4*)(Ar + (m << 3));   // ds_read_b128, batched+independent
    Areg[4 * m + 0] = q.x; Areg[4 * m + 1] = q.y;
    Areg[4 * m + 2] = q.z; Areg[4 * m + 3] = q.w;
  }
  float k1 = rk4_dot(Areg, vr);
  vr[lane] = fmaf(0.5f, k1, y);
  float k2 = rk4_dot(Areg, vr);
  vr[lane] = fmaf(0.5f, k2, y);
  float k3 = rk4_dot(Areg, vr);
  vr[lane] = y + k3;
  float k4 = rk4_dot(Areg, vr);
  float yn = y + (k1 + 2.f * k2 + 2.f * k3 + k4) * (1.f / 6.f);
  vr[lane] = yn;                             // stage-1 vector for next step
  return yn;
}

__global__ void __launch_bounds__(1024, 4) k_main(
    const float* __restrict__ y0, const float* __restrict__ dW,
    const unsigned short* __restrict__ G2T, const int* __restrict__ perm,
    const int* __restrict__ idxb, float* __restrict__ out)
{
  __shared__ __align__(16) unsigned short Abuf[16 * ESTR];  // 147712 B
  __shared__ __align__(16) unsigned short dwst[2][1024];    // 4096 B, 2 steps' dw frags
  __shared__ __align__(16) float vbuf[16 * 64];             // 4096 B stage vectors
  __shared__ int meta_b[16], meta_i[16], chunk_max;

  const int t = threadIdx.x;
  const int lane = t & 63;
  const int wave = t >> 6;                   // wave == element for RK4

  // interleave chunk->block mapping so per-CU work (sorted step counts) balances
  int W = blockIdx.x;
  int c = (W & 1) ? (NCHUNK - 1 - (W >> 1)) : (W >> 1);

  if (t < 16) {
    int b = perm[(c << 4) + t];
    meta_b[t] = b;
    meta_i[t] = idxb[b];
  }
  __syncthreads();
  if (t == 0) {
    int m = 0;
    for (int e = 0; e < 16; ++e) m = max(m, meta_i[e]);
    chunk_max = m;
  }
  const int my_b = meta_b[wave];
  const int my_idx = meta_i[wave];
  float y = y0[my_b * 64 + lane];
  vbuf[(wave << 6) + lane] = y;
  __syncthreads();
  const int nsteps = chunk_max + 1;
  const int npass = (nsteps + 1) >> 1;

  const int fl = lane & 15;                  // frag row index / elem-col in D
  const int fq = lane >> 4;                  // frag quad
  const int di = ((lane >> 3) << 7) + (wave << 3) + (lane & 7);  // dw staging slot
  float* vr = &vbuf[wave << 6];

  // preload pass-0 dW (always in range: s1 <= nsteps <= 100 -> s1 <= 99 when used)
  float dv0 = dW[(0 * BATCH + my_b) * 64 + lane];
  float dv1 = dW[(1 * BATCH + my_b) * 64 + lane];

  for (int p = 0; p < npass; ++p) {
    const int s0 = 2 * p, s1 = 2 * p + 1;
    // ---- stage both steps' dw, bf16, MFMA B-frag order
    dwst[0][di] = f2bf(dv0);
    dwst[1][di] = f2bf(dv1);
    // prefetch next pass's dW (consumed next iteration; hides HBM latency)
    if (p + 1 < npass) {
      dv0 = dW[((s0 + 2) * BATCH + my_b) * 64 + lane];
      dv1 = dW[((s1 + 2) * BATCH + my_b) * 64 + lane];
    }
    __syncthreads();

    // ---- dual-step A-build: D[n][e] = sum_k G[n][k] dw_e[k]
    short8 a0s = *(const short8*)(&dwst[0][lane << 3]);        // step s0, k 0..31
    short8 a1s = *(const short8*)(&dwst[0][512 + (lane << 3)]);// step s0, k 32..63
    short8 a0t = *(const short8*)(&dwst[1][lane << 3]);        // step s1
    short8 a1t = *(const short8*)(&dwst[1][512 + (lane << 3)]);
    unsigned h0[16], h1[16];                 // held step-s1 A (bf16 packed)
#pragma unroll
    for (int tt = 0; tt < 16; ++tt) {
      int nt = wave + (tt << 4);
      int n = (nt << 4) + fl;                // G-frag row (MFMA A-operand)
      const unsigned short* gp = &G2T[(n << 6) + (fq << 3)];
      short8 g0 = *(const short8*)(gp);
      short8 g1 = *(const short8*)(gp + 32);
      f32x4 acc = {0.f, 0.f, 0.f, 0.f};
      acc = __builtin_amdgcn_mfma_f32_16x16x32_bf16(g0, a0s, acc, 0, 0, 0);
      acc = __builtin_amdgcn_mfma_f32_16x16x32_bf16(g1, a1s, acc, 0, 0, 0);
      f32x4 acc2 = {0.f, 0.f, 0.f, 0.f};
      acc2 = __builtin_amdgcn_mfma_f32_16x16x32_bf16(g0, a0t, acc2, 0, 0, 0);
      acc2 = __builtin_amdgcn_mfma_f32_16x16x32_bf16(g1, a1t, acc2, 0, 0, 0);
      // D layout: col = fl = elem, rows = n-within-tile = fq*4 + r -> 4 consecutive n
      int i = nt >> 2;
      int j0 = ((nt & 3) << 4) + (fq << 2);
      uint2* dst = (uint2*)&Abuf[fl * ESTR + i * ISTR + j0];
      *dst = make_uint2(pack2(acc[0], acc[1]), pack2(acc[2], acc[3]));
      h0[tt] = pack2(acc2[0], acc2[1]);
      h1[tt] = pack2(acc2[2], acc2[3]);
    }
    __syncthreads();

    // ---- RK4 step s0 (A in registers)
    {
      float yn = rk4_one(&Abuf[wave * ESTR + lane * ISTR], vr, y, lane);
      if (s0 == my_idx) out[my_b * 64 + lane] = yn;
      y = yn;
    }
    __syncthreads();

    // ---- write held step-s1 A into Abuf
#pragma unroll
    for (int tt = 0; tt < 16; ++tt) {
      int nt = wave + (tt << 4);
      int i = nt >> 2;
      int j0 = ((nt & 3) << 4) + (fq << 2);
      uint2* dst = (uint2*)&Abuf[fl * ESTR + i * ISTR + j0];
      *dst = make_uint2(h0[tt], h1[tt]);
    }
    __syncthreads();

    // ---- RK4 step s1 (block-uniform predicate)
    if (s1 < nsteps) {
      float yn = rk4_one(&Abuf[wave * ESTR + lane * ISTR], vr, y, lane);
      if (s1 == my_idx) out[my_b * 64 + lane] = yn;
      y = yn;
    }
  }
}

// ---------------- launch ----------------

extern "C" void kernel_launch(void* const* d_in, const int* in_sizes, int n_in,
                              void* d_out, int out_size, void* d_ws, size_t ws_size,
                              hipStream_t stream) {
  const float* y0 = (const float*)d_in[0];
  const float* tv = (const float*)d_in[1];
  const float* G  = (const float*)d_in[2];
  const float* dW = (const float*)d_in[3];
  float* out = (float*)d_out;

  char* w = (char*)d_ws;
  unsigned short* g2 = (unsigned short*)w;          // 512 KB bf16 G table
  int* idxb = (int*)(w + 524288);                   // 64 KB
  int* perm = (int*)(w + 524288 + 65536);           // 64 KB
  int* hist = (int*)(w + 524288 + 131072);          // 128 ints
  int* offs = hist + 128;
  int* cur  = hist + 256;

  hipMemsetAsync(hist, 0, 1536, stream);            // zero hist+offs+cur
  k_cast<<<1024, 256, 0, stream>>>(G, g2, 64 * 64 * 64);
  k_idx<<<64, 256, 0, stream>>>(tv, idxb, hist);
  k_scan<<<1, 64, 0, stream>>>(hist, offs);
  k_scatter<<<64, 256, 0, stream>>>(idxb, offs, cur, perm);
  k_main<<<NCHUNK, 1024, 0, stream>>>(y0, dW, g2, perm, idxb, out);
}

// Round 3
// 2624.261 us; speedup vs baseline: 2.6396x; 2.6396x over previous
//
#include <hip/hip_runtime.h>

// multiplicativeNoise: dY = G(Y) o dB  (mu_strato == 0 exactly), 100-step RK4,
// per-sample gather at step idx[b] = clip(trunc(100*t[b]), 0, 99).
//
// Round-3 structure:
//  - counting-sort batch by idx; 16 elems per block (1024 thr), early exit.
//  - G pre-swizzled into MFMA A-operand fragment order (G2S[tile][lane][chunk]):
//    build-phase G loads are lane-contiguous b128s (round 1/2 read lane-strided
//    16B at 128B stride = 64 cache lines per instruction -> TA-serialization was
//    the real round-1 bottleneck, ~50k stall cyc/step).
//  - A-build GEMM: D[n][e] = sum_k G[n][k] dw_e[k]; packed b64 LDS stores.
//  - RK4: wave e loads its elem's A row into 32 VGPRs (8x b128), stages are
//    16 broadcast vbuf reads + 64 FMA. Wave-implicit stage sync.
//  - S=1 (no held fragments): 16-wave blocks cap unified VGPR+AGPR at 128/lane;
//    round 2's held S=2 fragments spilled to scratch -> L2 thrash -> G fell out
//    of L2 (13.6 GB HBM fetch). Keep pressure ~70 regs, launch_bounds(1024,1).
//  - dW prefetched one step ahead (registers).

typedef __attribute__((ext_vector_type(8))) short short8;
typedef __attribute__((ext_vector_type(4))) float f32x4;

#define NSTEP 100
#define BATCH 16384
#define NCHUNK 1024            // BATCH / 16
#define ISTR 72                // ushort stride per A row i (64 + 8 pad = 144B, 16B aligned)
#define ESTR 4616              // ushort stride per elem (64*72 + 8 pad = 9232B, 16B aligned)

__device__ __forceinline__ unsigned short f2bf(float f) {
  unsigned u = __float_as_uint(f);
  unsigned r = (u + 0x7FFFu + ((u >> 16) & 1u)) >> 16;   // RNE
  return (unsigned short)r;
}
__device__ __forceinline__ unsigned pack2(float a, float b) {
  return (unsigned)f2bf(a) | ((unsigned)f2bf(b) << 16);
}
__device__ __forceinline__ float bflo(unsigned u) { return __uint_as_float(u << 16); }
__device__ __forceinline__ float bfhi(unsigned u) { return __uint_as_float(u & 0xffff0000u); }

// ---------------- prep kernels ----------------

// Swizzle G (fp32, flat (i*64+j)*64+k = n*64+k) into bf16 MFMA-A-fragment order:
// per 16-row tile nt, lane l (= fq*16+fl) owns rows n = nt*16+fl, k = c*32+fq*8+j
// stored at G2S[nt*1024 + l*16 + c*8 + j]  (ushort units; 32 B contiguous per lane).
__global__ void k_swz(const float* __restrict__ G, unsigned short* __restrict__ g2s) {
  int o = blockIdx.x * blockDim.x + threadIdx.x;      // 262144 outputs
  if (o < 64 * 64 * 64) {
    int nt = o >> 10;
    int r  = o & 1023;
    int l  = r >> 4;
    int c  = (r >> 3) & 1;
    int j  = r & 7;
    int n  = (nt << 4) + (l & 15);
    int k  = (c << 5) + ((l >> 4) << 3) + j;
    g2s[o] = f2bf(G[(n << 6) + k]);
  }
}

__global__ void k_idx(const float* __restrict__ t, int* __restrict__ idxb, int* __restrict__ hist) {
  int b = blockIdx.x * blockDim.x + threadIdx.x;
  if (b < BATCH) {
    int ix = (int)truncf(100.0f * t[b]);       // matches jnp.trunc(n*t/T) in fp32
    ix = min(max(ix, 0), NSTEP - 1);
    idxb[b] = ix;
    atomicAdd(&hist[ix], 1);
  }
}

__global__ void k_scan(const int* __restrict__ hist, int* __restrict__ offs) {
  if (threadIdx.x == 0 && blockIdx.x == 0) {
    int run = 0;
    for (int i = 0; i < NSTEP; ++i) { offs[i] = run; run += hist[i]; }
  }
}

__global__ void k_scatter(const int* __restrict__ idxb, const int* __restrict__ offs,
                          int* __restrict__ cur, int* __restrict__ perm) {
  int b = blockIdx.x * blockDim.x + threadIdx.x;
  if (b < BATCH) {
    int ix = idxb[b];
    int pos = offs[ix] + atomicAdd(&cur[ix], 1);
    perm[pos] = b;
  }
}

// ---------------- main kernel ----------------

__device__ __forceinline__ float rk4_dot(const unsigned* Ap, const float* vr) {
  // 4 partial accumulators: FMA dep chain 16 deep instead of 64
  float a0 = 0.f, a1 = 0.f, a2 = 0.f, a3 = 0.f;
#pragma unroll
  for (int m = 0; m < 16; ++m) {
    float4 v = ((const float4*)vr)[m];      // broadcast LDS read (conflict-free)
    unsigned ua = Ap[2 * m], ub = Ap[2 * m + 1];
    a0 = fmaf(bflo(ua), v.x, a0);
    a1 = fmaf(bfhi(ua), v.y, a1);
    a2 = fmaf(bflo(ub), v.z, a2);
    a3 = fmaf(bfhi(ub), v.w, a3);
  }
  return (a0 + a1) + (a2 + a3);
}

__device__ __forceinline__ float rk4_one(const unsigned short* Ar, float* vr, float y, int lane) {
  unsigned Areg[32];                         // this elem's A row (64 bf16), registers
#pragma unroll
  for (int m = 0; m < 8; ++m) {
    uint4 q = *(const uint4*)(Ar + (m << 3));   // ds_read_b128, batched+independent
    Areg[4 * m + 0] = q.x; Areg[4 * m + 1] = q.y;
    Areg[4 * m + 2] = q.z; Areg[4 * m + 3] = q.w;
  }
  float k1 = rk4_dot(Areg, vr);
  vr[lane] = fmaf(0.5f, k1, y);
  float k2 = rk4_dot(Areg, vr);
  vr[lane] = fmaf(0.5f, k2, y);
  float k3 = rk4_dot(Areg, vr);
  vr[lane] = y + k3;
  float k4 = rk4_dot(Areg, vr);
  float yn = y + (k1 + 2.f * k2 + 2.f * k3 + k4) * (1.f / 6.f);
  vr[lane] = yn;                             // stage-1 vector for next step
  return yn;
}

__global__ void __launch_bounds__(1024, 1) k_main(
    const float* __restrict__ y0, const float* __restrict__ dW,
    const unsigned short* __restrict__ G2S, const int* __restrict__ perm,
    const int* __restrict__ idxb, float* __restrict__ out)
{
  __shared__ __align__(16) unsigned short Abuf[16 * ESTR];  // 147712 B
  __shared__ __align__(16) unsigned short dwst[1024];       // 2048 B dw frags
  __shared__ __align__(16) float vbuf[16 * 64];             // 4096 B stage vectors
  __shared__ int meta_b[16], meta_i[16], chunk_max;

  const int t = threadIdx.x;
  const int lane = t & 63;
  const int wave = t >> 6;                   // wave == element for RK4

  // interleave chunk->block mapping so per-CU work (sorted step counts) balances
  int W = blockIdx.x;
  int c = (W & 1) ? (NCHUNK - 1 - (W >> 1)) : (W >> 1);

  if (t < 16) {
    int b = perm[(c << 4) + t];
    meta_b[t] = b;
    meta_i[t] = idxb[b];
  }
  __syncthreads();
  if (t == 0) {
    int m = 0;
    for (int e = 0; e < 16; ++e) m = max(m, meta_i[e]);
    chunk_max = m;
  }
  const int my_b = meta_b[wave];
  const int my_idx = meta_i[wave];
  float y = y0[my_b * 64 + lane];
  vbuf[(wave << 6) + lane] = y;
  __syncthreads();
  const int nsteps = chunk_max + 1;

  const int fl = lane & 15;                  // frag row index / elem-col in D
  const int fq = lane >> 4;                  // frag quad
  const int di = ((lane >> 3) << 7) + (wave << 3) + (lane & 7);  // dw staging slot
  float* vr = &vbuf[wave << 6];

  float dv = dW[(0 * BATCH + my_b) * 64 + lane];   // step-0 dw, prefetched

  for (int s = 0; s < nsteps; ++s) {
    // ---- stage dw (bf16, MFMA B-frag order), prefetch next step's dw
    dwst[di] = f2bf(dv);
    if (s + 1 < nsteps) dv = dW[((s + 1) * BATCH + my_b) * 64 + lane];
    __syncthreads();

    // ---- A-build: D[n][e] = sum_k G[n][k] dw_e[k]; wave w owns tiles w+16*tt
    {
      short8 a0 = *(const short8*)(&dwst[lane << 3]);        // k 0..31
      short8 a1 = *(const short8*)(&dwst[512 + (lane << 3)]);// k 32..63
#pragma unroll 4
      for (int tt = 0; tt < 16; ++tt) {
        int nt = wave + (tt << 4);
        const unsigned short* gp = &G2S[(nt << 10) + (lane << 4)];  // coalesced
        short8 g0 = *(const short8*)(gp);
        short8 g1 = *(const short8*)(gp + 8);
        f32x4 acc = {0.f, 0.f, 0.f, 0.f};
        acc = __builtin_amdgcn_mfma_f32_16x16x32_bf16(g0, a0, acc, 0, 0, 0);
        acc = __builtin_amdgcn_mfma_f32_16x16x32_bf16(g1, a1, acc, 0, 0, 0);
        // D layout: col = fl = elem, rows = fq*4 + r -> 4 consecutive n
        int i = nt >> 2;
        int j0 = ((nt & 3) << 4) + (fq << 2);
        uint2* dst = (uint2*)&Abuf[fl * ESTR + i * ISTR + j0];
        *dst = make_uint2(pack2(acc[0], acc[1]), pack2(acc[2], acc[3]));
      }
    }
    __syncthreads();

    // ---- RK4 (A in registers; stage sync wave-implicit). No trailing barrier:
    // next iteration's stage->build barrier orders RK4 reads vs Abuf rewrite.
    {
      float yn = rk4_one(&Abuf[wave * ESTR + lane * ISTR], vr, y, lane);
      if (s == my_idx) out[my_b * 64 + lane] = yn;
      y = yn;
    }
  }
}

// ---------------- launch ----------------

extern "C" void kernel_launch(void* const* d_in, const int* in_sizes, int n_in,
                              void* d_out, int out_size, void* d_ws, size_t ws_size,
                              hipStream_t stream) {
  const float* y0 = (const float*)d_in[0];
  const float* tv = (const float*)d_in[1];
  const float* G  = (const float*)d_in[2];
  const float* dW = (const float*)d_in[3];
  float* out = (float*)d_out;

  char* w = (char*)d_ws;
  unsigned short* g2s = (unsigned short*)w;         // 512 KB bf16 swizzled G
  int* idxb = (int*)(w + 524288);                   // 64 KB
  int* perm = (int*)(w + 524288 + 65536);           // 64 KB
  int* hist = (int*)(w + 524288 + 131072);          // 128 ints
  int* offs = hist + 128;
  int* cur  = hist + 256;

  hipMemsetAsync(hist, 0, 1536, stream);            // zero hist+offs+cur
  k_swz<<<1024, 256, 0, stream>>>(G, g2s);
  k_idx<<<64, 256, 0, stream>>>(tv, idxb, hist);
  k_scan<<<1, 64, 0, stream>>>(hist, offs);
  k_scatter<<<64, 256, 0, stream>>>(idxb, offs, cur, perm);
  k_main<<<NCHUNK, 1024, 0, stream>>>(y0, dW, g2s, perm, idxb, out);
}